// Round 8
// baseline (278.570 us; speedup 1.0000x reference)
//
#include <hip/hip_runtime.h>

// ---- problem constants ----
static constexpr int kN = 64;    // nodes
static constexpr int kD = 1024;  // feature dim
static constexpr int kE = 1024;  // edges (16 per row, row-major by (i,j))
static constexpr int kT = 2;     // iterations

typedef short  bf16x8 __attribute__((ext_vector_type(8)));
typedef float  f32x4  __attribute__((ext_vector_type(4)));
typedef unsigned short us8 __attribute__((ext_vector_type(8)));
typedef unsigned short us4 __attribute__((ext_vector_type(4)));

__device__ __forceinline__ unsigned short f2b(float f) {
    unsigned int u = __builtin_bit_cast(unsigned int, f);
    u += 0x7FFFu + ((u >> 16) & 1u);          // RNE
    return (unsigned short)(u >> 16);
}
__device__ __forceinline__ float b2f(unsigned short u) {
    unsigned int x = ((unsigned int)u) << 16;
    return __builtin_bit_cast(float, x);
}
__device__ __forceinline__ bf16x8 cvt8(float4 a, float4 b) {
    us8 o;
    o[0] = f2b(a.x); o[1] = f2b(a.y); o[2] = f2b(a.z); o[3] = f2b(a.w);
    o[4] = f2b(b.x); o[5] = f2b(b.y); o[6] = f2b(b.z); o[7] = f2b(b.w);
    return __builtin_bit_cast(bf16x8, o);
}

// A-operand source, ALL bf16 [row][1024] segments:
// mode 1: concat of segments s0|s1|s2 ; mode 2: [s0 | s0*s1]
struct ASrc { const unsigned short* s0; const unsigned short* s1; const unsigned short* s2; int mode; };

__device__ __forceinline__ bf16x8 loadA8(const ASrc& s, int row, int kg) {
    const int seg = kg >> 10, k = kg & 1023;
    const size_t ro = (size_t)row * 1024 + k;
    if (s.mode == 1) {
        const unsigned short* p = (seg == 0) ? s.s0 : (seg == 1 ? s.s1 : s.s2);
        return *(const bf16x8*)(p + ro);
    }
    const bf16x8 a = *(const bf16x8*)(s.s0 + ro);
    if (seg == 0) return a;
    const bf16x8 b = *(const bf16x8*)(s.s1 + ro);
    const us8 ua = __builtin_bit_cast(us8, a), ub = __builtin_bit_cast(us8, b);
    us8 o;
#pragma unroll
    for (int q = 0; q < 8; ++q) o[q] = f2b(b2f(ua[q]) * b2f(ub[q]));
    return __builtin_bit_cast(bf16x8, o);
}

// =====================================================================
// Job-list MFMA GEMM.
// BIG path (M>=128): 128x128 tile, 4 waves (2x2) each 64x64. A staged
//   through swizzled LDS; B streamed from global in MFMA-frag layout with
//   ping-pong register prefetch (no LDS). bf16 partials, LDS-coalesced.
// SKINNY path (M=64): 64x128 tile as before (A+B via LDS), f32 partials.
// Block decode: row-tile fastest -> XCD-affine A reuse in L2.
// =====================================================================
struct GJob { ASrc a; const unsigned short* W; int ldw; void* P; int M; int K; int KS; int pbf; };
struct GJobs { GJob j[5]; int t0[6]; int nj; };

__global__ __launch_bounds__(256)
void k_gemm(GJobs G)
{
    __shared__ unsigned short lds[16896];
    const int flat = blockIdx.x;
    int ji = 0;
    while (ji + 1 < G.nj && flat >= G.t0[ji + 1]) ++ji;
    const GJob J = G.j[ji];
    const int local = flat - G.t0[ji];
    const int tid = threadIdx.x, lane = tid & 63, wid = tid >> 6;
    const int l15 = lane & 15, l4 = lane >> 4;
    const int sr = tid >> 3, sc8 = tid & 7;
    const int wc8 = (sc8 ^ (sr & 7)) * 8;

    if (J.M >= 128) {
        // ---------------- BIG: 128x128 ----------------
        const int rowTiles = J.M >> 7;
        const int rt = local % rowTiles;
        const int rest = local / rowTiles;
        const int ct = rest & 7, z = rest >> 3;
        const int rowBase = rt * 128, colBase = ct * 128;
        const int kchunk = J.K / J.KS, kbeg = z * kchunk, kend = kbeg + kchunk;
        const int wr = wid >> 1, wc = wid & 1;

        f32x4 acc[4][4] = {};
        bf16x8 ra[4], rb0[8], rb1[8];
        const unsigned short* Bbase =
            J.W + (size_t)(colBase + wc * 64 + l15) * J.ldw + l4 * 8;

        auto stageA = [&](int kt) {
#pragma unroll
            for (int h = 0; h < 4; ++h)
                ra[h] = loadA8(J.a, rowBase + sr + 32 * h, kt + sc8 * 8);
        };
        auto loadB = [&](int kt, bf16x8* rb) {
#pragma unroll
            for (int n = 0; n < 4; ++n) {
                rb[n]     = *(const bf16x8*)(Bbase + (size_t)(n * 16) * J.ldw + kt);
                rb[4 + n] = *(const bf16x8*)(Bbase + (size_t)(n * 16) * J.ldw + kt + 32);
            }
        };
        auto writeA = [&]() {
#pragma unroll
            for (int h = 0; h < 4; ++h)
                *(bf16x8*)&lds[(sr + 32 * h) * 64 + wc8] = ra[h];
        };
        auto compute = [&](bf16x8* rb) {
#pragma unroll
            for (int kk = 0; kk < 2; ++kk) {
                bf16x8 af[4];
#pragma unroll
                for (int m = 0; m < 4; ++m) {
                    const int ar = wr * 64 + m * 16 + l15;
                    af[m] = *(const bf16x8*)&lds[ar * 64 + (((kk << 2) | l4) ^ (ar & 7)) * 8];
                }
#pragma unroll
                for (int m = 0; m < 4; ++m)
#pragma unroll
                    for (int n = 0; n < 4; ++n)
                        acc[m][n] = __builtin_amdgcn_mfma_f32_16x16x32_bf16(
                            af[m], rb[kk * 4 + n], acc[m][n], 0, 0, 0);
            }
        };

        stageA(kbeg); loadB(kbeg, rb0);
        for (int kt = kbeg; kt < kend; kt += 128) {
            __syncthreads();
            writeA();
            __syncthreads();
            const bool more1 = (kt + 64 < kend);
            if (more1) { stageA(kt + 64); loadB(kt + 64, rb1); }
            compute(rb0);
            if (!more1) break;
            __syncthreads();
            writeA();
            __syncthreads();
            const bool more2 = (kt + 128 < kend);
            if (more2) { stageA(kt + 128); loadB(kt + 128, rb0); }
            compute(rb1);
        }

        // bf16 partial epilogue via LDS (coalesced)
        __syncthreads();
#pragma unroll
        for (int m = 0; m < 4; ++m)
#pragma unroll
            for (int n = 0; n < 4; ++n)
#pragma unroll
                for (int r = 0; r < 4; ++r)
                    lds[(wr * 64 + m * 16 + l4 * 4 + r) * 132 + wc * 64 + n * 16 + l15] =
                        f2b(acc[m][n][r]);
        __syncthreads();
        unsigned short* Pb = (unsigned short*)J.P + (size_t)z * J.M * 1024;
#pragma unroll
        for (int c = tid; c < 2048; c += 256) {
            const int row = c >> 4, ch = c & 15;
            *(bf16x8*)(Pb + (size_t)(rowBase + row) * 1024 + colBase + ch * 8) =
                *(const bf16x8*)&lds[row * 132 + ch * 8];
        }
    } else {
        // ---------------- SKINNY: 64x128, f32 partials ----------------
        const int ct = local & 7, z = local >> 3;
        const int colBase = ct * 128;
        const int kchunk = J.K / J.KS, kbeg = z * kchunk, kend = kbeg + kchunk;
        const int wr = wid >> 1, wc = wid & 1;

        bf16x8 ra[2], rb[4];
        auto stage = [&](int kt) {
#pragma unroll
            for (int h = 0; h < 2; ++h)
                ra[h] = loadA8(J.a, sr + 32 * h, kt + sc8 * 8);
#pragma unroll
            for (int h = 0; h < 4; ++h)
                rb[h] = *(const bf16x8*)(J.W + (size_t)(colBase + sr + 32 * h) * J.ldw + kt + sc8 * 8);
        };

        f32x4 acc[2][4] = {};
        stage(kbeg);
        for (int kt = kbeg; kt < kend; kt += 64) {
            __syncthreads();
#pragma unroll
            for (int h = 0; h < 2; ++h)
                *(bf16x8*)&lds[(sr + 32 * h) * 64 + wc8] = ra[h];
#pragma unroll
            for (int h = 0; h < 4; ++h)
                *(bf16x8*)&lds[4096 + (sr + 32 * h) * 64 + wc8] = rb[h];
            __syncthreads();
            if (kt + 64 < kend) stage(kt + 64);
#pragma unroll
            for (int kk = 0; kk < 2; ++kk) {
                const int c8 = kk * 4 + l4;
                bf16x8 af[2], bv[4];
#pragma unroll
                for (int m = 0; m < 2; ++m) {
                    const int ar = wr * 32 + m * 16 + l15;
                    af[m] = *(const bf16x8*)&lds[ar * 64 + (c8 ^ (ar & 7)) * 8];
                }
#pragma unroll
                for (int n = 0; n < 4; ++n) {
                    const int br = wc * 64 + n * 16 + l15;
                    bv[n] = *(const bf16x8*)&lds[4096 + br * 64 + (c8 ^ (br & 7)) * 8];
                }
#pragma unroll
                for (int m = 0; m < 2; ++m)
#pragma unroll
                    for (int n = 0; n < 4; ++n)
                        acc[m][n] = __builtin_amdgcn_mfma_f32_16x16x32_bf16(af[m], bv[n], acc[m][n], 0, 0, 0);
            }
        }
        float* base = (float*)J.P + (size_t)z * J.M * 1024;
#pragma unroll
        for (int m = 0; m < 2; ++m) {
            const int row = wr * 32 + m * 16 + l4 * 4;
#pragma unroll
            for (int n = 0; n < 4; ++n) {
                const int col = colBase + wc * 64 + n * 16 + l15;
#pragma unroll
                for (int r = 0; r < 4; ++r)
                    base[(size_t)(row + r) * 1024 + col] = acc[m][n][r];
            }
        }
    }
}

// =====================================================================
// Job-list split-K reduce, 8-elem granularity.
// out = sum_z P[z] (+addb bf16) (+bias) (+gather a_s/a_o from f32 partials)
// =====================================================================
struct RJob { const void* P; int MO8; int KS; int pbf; float* Cf; unsigned short* Cb;
              const unsigned short* addb; const float* bias; int gather; };
struct RJobs { RJob j[6]; int t0[7]; int nj; const int* eidx; const float* gP; int gKS; };

__global__ void k_reduce(RJobs R)
{
    const int flat = blockIdx.x;
    int ji = 0;
    while (ji + 1 < R.nj && flat >= R.t0[ji + 1]) ++ji;
    const RJob J = R.j[ji];
    const int i8 = (flat - R.t0[ji]) * 256 + threadIdx.x;
    if (i8 >= J.MO8) return;
    float s[8] = {0.f, 0.f, 0.f, 0.f, 0.f, 0.f, 0.f, 0.f};
    if (J.pbf) {
        const unsigned short* P = (const unsigned short*)J.P;
        for (int z = 0; z < J.KS; ++z) {
            const us8 v = *(const us8*)(P + (size_t)z * J.MO8 * 8 + (size_t)i8 * 8);
#pragma unroll
            for (int q = 0; q < 8; ++q) s[q] += b2f(v[q]);
        }
    } else {
        const float* P = (const float*)J.P;
        for (int z = 0; z < J.KS; ++z) {
            const float* p = P + (size_t)z * J.MO8 * 8 + (size_t)i8 * 8;
            const float4 v0 = *(const float4*)p;
            const float4 v1 = *(const float4*)(p + 4);
            s[0] += v0.x; s[1] += v0.y; s[2] += v0.z; s[3] += v0.w;
            s[4] += v1.x; s[5] += v1.y; s[6] += v1.z; s[7] += v1.w;
        }
    }
    if (J.addb) {
        const us8 v = *(const us8*)(J.addb + (size_t)i8 * 8);
#pragma unroll
        for (int q = 0; q < 8; ++q) s[q] += b2f(v[q]);
    }
    if (J.gather) {
        const int e = i8 >> 7, c8 = i8 & 127;
        const int idx = R.eidx[e];
        const float* as_ = R.gP + (size_t)(idx >> 6) * 1024 + c8 * 8;
        const float* ao_ = R.gP + 131072 + (size_t)(idx & 63) * 1024 + c8 * 8;
        for (int z = 0; z < R.gKS; ++z) {
#pragma unroll
            for (int q = 0; q < 8; ++q)
                s[q] += as_[(size_t)z * 65536 + q] + ao_[(size_t)z * 65536 + q];
        }
    }
    if (J.bias) {
        const int c8 = i8 & 127;
#pragma unroll
        for (int q = 0; q < 8; ++q) s[q] += J.bias[c8 * 8 + q];
    }
    if (J.Cf) {
        *(float4*)(J.Cf + (size_t)i8 * 8)     = make_float4(s[0], s[1], s[2], s[3]);
        *(float4*)(J.Cf + (size_t)i8 * 8 + 4) = make_float4(s[4], s[5], s[6], s[7]);
    }
    if (J.Cb) {
        us8 o;
#pragma unroll
        for (int q = 0; q < 8; ++q) o[q] = f2b(s[q]);
        *(us8*)(J.Cb + (size_t)i8 * 8) = o;
    }
}

// batched f32 -> bf16 conversion (7 matrices), one launch
struct ConvBatch { const float* s[7]; unsigned short* d[7]; int beg8[7]; int total8; };
__global__ void k_f2b_batch(ConvBatch cb)
{
    int i = blockIdx.x * blockDim.x + threadIdx.x;
    if (i >= cb.total8) return;
    int k = 0;
    while (k < 6 && i >= cb.beg8[k + 1]) ++k;
    const int j = i - cb.beg8[k];
    const float4 v0 = reinterpret_cast<const float4*>(cb.s[k])[2 * j];
    const float4 v1 = reinterpret_cast<const float4*>(cb.s[k])[2 * j + 1];
    const bf16x8 o = cvt8(v0, v1);
    *(bf16x8*)(cb.d[k] + (size_t)j * 8) = o;
}

// transpose 4 f32 [1024][1024] matrices into bf16 (dst[k][o] = src[o][k])
struct T4 { const float* s[4]; unsigned short* d[4]; };
__global__ __launch_bounds__(256)
void k_transpose(T4 t4)
{
    __shared__ float tile[64][65];
    const float* __restrict__ src = t4.s[blockIdx.z];
    unsigned short* __restrict__ dst = t4.d[blockIdx.z];
    const int bx = blockIdx.x * 64, by = blockIdx.y * 64;
    const int c = threadIdx.x & 63, r0 = threadIdx.x >> 6;
#pragma unroll
    for (int h = 0; h < 16; ++h) {
        const int r = r0 * 16 + h;
        tile[r][c] = src[(size_t)(by + r) * 1024 + bx + c];
    }
    __syncthreads();
#pragma unroll
    for (int h = 0; h < 16; ++h) {
        const int kk = r0 * 16 + h;
        dst[(size_t)(bx + kk) * 1024 + by + c] = f2b(tile[c][kk]);
    }
}

// build folded joint weights from W (1024 x 4096, slices W1|W2|W3|W4):
// z=0 (rel, s=+1):  rt = W1+W4,  eff = [W2-W4 | W3]
// z=1 (vj,  s=-1):  rt = W1-W4,  eff = [W2+W4 | W3]
__global__ __launch_bounds__(256)
void k_buildW(const float* __restrict__ Wrel, const float* __restrict__ Wjnt,
              unsigned short* __restrict__ WrtRel, unsigned short* __restrict__ WeffRel,
              unsigned short* __restrict__ UrtVj, unsigned short* __restrict__ UeffVj)
{
    const int idx = blockIdx.x * 256 + threadIdx.x;     // [0, 1024*256)
    const int o = idx >> 8, j = (idx & 255) * 4;
    const float* W = blockIdx.z ? Wjnt : Wrel;
    const float sgn = blockIdx.z ? -1.f : 1.f;
    unsigned short* rt = blockIdx.z ? UrtVj : WrtRel;
    unsigned short* ef = blockIdx.z ? UeffVj : WeffRel;
    const float4 w1 = *(const float4*)(W + (size_t)o * 4096 + j);
    const float4 w2 = *(const float4*)(W + (size_t)o * 4096 + 1024 + j);
    const float4 w3 = *(const float4*)(W + (size_t)o * 4096 + 2048 + j);
    const float4 w4 = *(const float4*)(W + (size_t)o * 4096 + 3072 + j);
    us4 t;
    t.x = f2b(w1.x + sgn * w4.x); t.y = f2b(w1.y + sgn * w4.y);
    t.z = f2b(w1.z + sgn * w4.z); t.w = f2b(w1.w + sgn * w4.w);
    *(us4*)(rt + (size_t)o * 1024 + j) = t;
    t.x = f2b(w2.x - sgn * w4.x); t.y = f2b(w2.y - sgn * w4.y);
    t.z = f2b(w2.z - sgn * w4.z); t.w = f2b(w2.w - sgn * w4.w);
    *(us4*)(ef + (size_t)o * 2048 + j) = t;
    t.x = f2b(w3.x); t.y = f2b(w3.y); t.z = f2b(w3.z); t.w = f2b(w3.w);
    *(us4*)(ef + (size_t)o * 2048 + 1024 + j) = t;
}

// =====================================================================
// merged scores + softmax + weighted aggregation.
// block i<64  : s[q] = <qws[i], relj[16i+q]>/32 ; ctx1[i] = softmax-weighted sum
// block j>=64 : s[i] = <qwo[j], relj[conn[i][j]]>/32 ; ctx2[j] likewise (col)
// =====================================================================
__global__ __launch_bounds__(256)
void k_sctx(const float* __restrict__ relj, const float* __restrict__ qws,
            const float* __restrict__ qwo, const int* __restrict__ conn,
            unsigned short* __restrict__ ctx1b, unsigned short* __restrict__ ctx2b)
{
    const int bid = blockIdx.x, t = threadIdx.x;
    const float4* relj4 = reinterpret_cast<const float4*>(relj);
    __shared__ float sl[64];
    __shared__ int el[64];
    float4 acc = make_float4(0.f, 0.f, 0.f, 0.f);

    if (bid < 64) {
        const int i = bid;
        // phase 1: scores (16 threads per edge)
        {
            const int g = t >> 4, l = t & 15;          // edge i*16+g
            const size_t e4 = (size_t)(i * 16 + g) * 256;
            const float4* q4 = reinterpret_cast<const float4*>(qws) + (size_t)i * 256;
            float v = 0.f;
#pragma unroll
            for (int q = 0; q < 16; ++q) {
                const float4 r = relj4[e4 + l + q * 16];
                const float4 a = q4[l + q * 16];
                v += a.x * r.x + a.y * r.y + a.z * r.z + a.w * r.w;
            }
            v += __shfl_xor(v, 1, 16);
            v += __shfl_xor(v, 2, 16);
            v += __shfl_xor(v, 4, 16);
            v += __shfl_xor(v, 8, 16);
            if (l == 0) sl[g] = v * 0.03125f;
        }
        __syncthreads();
        // phase 2: softmax + aggregate
        float sv[16];
        float m = -1e30f;
#pragma unroll
        for (int q = 0; q < 16; ++q) { sv[q] = sl[q]; m = fmaxf(m, sv[q]); }
        float sum = 0.f;
#pragma unroll
        for (int q = 0; q < 16; ++q) { sv[q] = expf(sv[q] - m); sum += sv[q]; }
        const float inv = 1.f / sum;
#pragma unroll
        for (int q = 0; q < 16; ++q) {
            const float w = sv[q] * inv;
            const float4 v = relj4[(size_t)(i * 16 + q) * 256 + t];
            acc.x += w * v.x; acc.y += w * v.y; acc.z += w * v.z; acc.w += w * v.w;
        }
        us4 o; o.x = f2b(acc.x); o.y = f2b(acc.y); o.z = f2b(acc.z); o.w = f2b(acc.w);
        *(us4*)(ctx1b + (size_t)i * 1024 + t * 4) = o;
    } else {
        const int j = bid - 64;
        // phase 1: scores (4 threads per row i)
        {
            const int i = t >> 2, sub = t & 3;
            const int e = conn[i * kN + j];
            if (sub == 0) el[i] = e;
            float v = 0.f;
            if (e >= 0) {
                const size_t e4 = (size_t)e * 256;
                const float4* q4 = reinterpret_cast<const float4*>(qwo) + (size_t)j * 256;
#pragma unroll
                for (int q = 0; q < 64; ++q) {
                    const float4 r = relj4[e4 + sub + q * 4];
                    const float4 a = q4[sub + q * 4];
                    v += a.x * r.x + a.y * r.y + a.z * r.z + a.w * r.w;
                }
            }
            v += __shfl_xor(v, 1, 4);
            v += __shfl_xor(v, 2, 4);
            if (sub == 0) sl[i] = (e >= 0) ? v * 0.03125f : -1e30f;
        }
        __syncthreads();
        // phase 2: softmax over column + aggregate
        float m = -1e30f;
        for (int i = 0; i < 64; ++i) m = fmaxf(m, sl[i]);
        float sum = 0.f;
        float ex[64];
        for (int i = 0; i < 64; ++i) {
            ex[i] = (el[i] >= 0) ? expf(sl[i] - m) : 0.f;
            sum += ex[i];
        }
        const float inv = 1.f / sum;
        for (int i = 0; i < 64; ++i) {
            const int e = el[i];
            if (e >= 0) {
                const float w = ex[i] * inv;
                const float4 v = relj4[(size_t)e * 256 + t];
                acc.x += w * v.x; acc.y += w * v.y; acc.z += w * v.z; acc.w += w * v.w;
            }
        }
        us4 o; o.x = f2b(acc.x); o.y = f2b(acc.y); o.z = f2b(acc.z); o.w = f2b(acc.w);
        *(us4*)(ctx2b + (size_t)j * 1024 + t * 4) = o;
    }
}

// =====================================================================
extern "C" void kernel_launch(void* const* d_in, const int* in_sizes, int n_in,
                              void* d_out, int out_size, void* d_ws, size_t ws_size,
                              hipStream_t stream)
{
    const float* visual   = (const float*)d_in[0];
    const float* relvis   = (const float*)d_in[1];
    const int*   conn     = (const int*)d_in[2];
    const int*   edge_idx = (const int*)d_in[4];
    const float* W_sub    = (const float*)d_in[5];
    const float* W_obj    = (const float*)d_in[6];
    const float* W_r2s    = (const float*)d_in[7];
    const float* W_r2o    = (const float*)d_in[8];
    const float* W_joint  = (const float*)d_in[9];
    const float* W_ctx    = (const float*)d_in[10];
    const float* W_relu   = (const float*)d_in[11];  // (D,3D): Ws|Wo|Wr
    const float* W_relj   = (const float*)d_in[12];
    const float* W_relc   = (const float*)d_in[13];
    const float* W_node   = (const float*)d_in[14];
    const float* b_node   = (const float*)d_in[15];
    const float* W_factor = (const float*)d_in[16];
    (void)in_sizes; (void)n_in; (void)out_size; (void)ws_size;

    float* ws = (float*)d_ws;
    size_t off = 0;
    auto allocF = [&](size_t n) { float* p = ws + off; off += n; return p; };
    auto allocU = [&](size_t n) { return (unsigned short*)allocF((n + 1) / 2); };

    float* partF = allocF((size_t)1024 * 1024);          // f32 partials (skinny)
    unsigned short* partB = allocU((size_t)16 * 1024 * 1024);  // bf16 partials
    float* asqw  = allocF((size_t)4 * 64 * 1024);        // a_s | a_o | qW_s | qW_o (f32)
    float* relj  = allocF((size_t)kE * kD);
    unsigned short* relvis_b = allocU((size_t)kE * kD);
    unsigned short* visual_b = allocU((size_t)kN * kD);
    unsigned short* vj_b   = allocU((size_t)kN * kD);
    unsigned short* rj_b   = allocU((size_t)kE * kD);
    unsigned short* relj_b = allocU((size_t)kE * kD);
    unsigned short* rc_bA  = allocU((size_t)kE * kD);
    unsigned short* rc_bB  = allocU((size_t)kE * kD);
    unsigned short* vctx_bA = allocU((size_t)kN * kD);
    unsigned short* vctx_bB = allocU((size_t)kN * kD);
    unsigned short* ctx1_b = allocU((size_t)kN * kD);
    unsigned short* ctx2_b = allocU((size_t)kN * kD);
    unsigned short* R0_b = allocU((size_t)kE * kD);
    unsigned short* G0_b = allocU((size_t)kN * kD);
    unsigned short* Wb_ctx    = allocU((size_t)kD * 3 * kD);
    unsigned short* Wb_relu   = allocU((size_t)kD * 3 * kD);
    unsigned short* Wb_relc   = allocU((size_t)kD * 2 * kD);
    unsigned short* Wb_node   = allocU((size_t)kD * 2 * kD);
    unsigned short* Wb_factor = allocU((size_t)kD * 2 * kD);
    unsigned short* WsubT = allocU((size_t)kD * kD);
    unsigned short* WobjT = allocU((size_t)kD * kD);
    unsigned short* Wr2sT = allocU((size_t)kD * kD);
    unsigned short* Wr2oT = allocU((size_t)kD * kD);
    unsigned short* Wc_s  = allocU((size_t)kD * kD);
    unsigned short* Wc_o  = allocU((size_t)kD * kD);
    unsigned short* WrtRel  = allocU((size_t)kD * kD);      // W1+W4
    unsigned short* WeffRel = allocU((size_t)kD * 2 * kD);  // [W2-W4 | W3]
    unsigned short* UrtVj   = allocU((size_t)kD * kD);      // U1-U4
    unsigned short* UeffVj  = allocU((size_t)kD * 2 * kD);  // [U2+U4 | U3]

    auto seg1 = [](const unsigned short* a) {
        ASrc s; s.s0 = a; s.s1 = nullptr; s.s2 = nullptr; s.mode = 1; return s;
    };
    auto seg2 = [](const unsigned short* a, const unsigned short* b) {
        ASrc s; s.s0 = a; s.s1 = b; s.s2 = nullptr; s.mode = 1; return s;
    };
    auto seg3 = [](const unsigned short* a, const unsigned short* b, const unsigned short* c) {
        ASrc s; s.s0 = a; s.s1 = b; s.s2 = c; s.mode = 1; return s;
    };
    auto prodA = [](const unsigned short* c, const unsigned short* x) {  // [c | c*x]
        ASrc s; s.s0 = c; s.s1 = x; s.s2 = nullptr; s.mode = 2; return s;
    };

    // ---- job-list launch helpers ----
    GJobs G; RJobs R;
    int gn = 0, gt = 0, rn = 0, rtt = 0;
    auto gAdd = [&](ASrc a, const unsigned short* W, int ldw, void* P, int M, int K, int KS, int pbf) {
        G.j[gn].a = a; G.j[gn].W = W; G.j[gn].ldw = ldw; G.j[gn].P = P;
        G.j[gn].M = M; G.j[gn].K = K; G.j[gn].KS = KS; G.j[gn].pbf = pbf;
        G.t0[gn] = gt;
        gt += (M >= 128) ? KS * (M >> 7) * 8 : KS * 8;
        ++gn;
    };
    auto gLaunch = [&]() {
        G.nj = gn; G.t0[gn] = gt;
        hipLaunchKernelGGL(k_gemm, dim3(gt), dim3(256), 0, stream, G);
        gn = 0; gt = 0;
    };
    auto rAdd = [&](const void* P, int MO8, int KS, int pbf, float* Cf, unsigned short* Cb,
                    const unsigned short* addb, const float* bias, int gather) {
        R.j[rn].P = P; R.j[rn].MO8 = MO8; R.j[rn].KS = KS; R.j[rn].pbf = pbf;
        R.j[rn].Cf = Cf; R.j[rn].Cb = Cb; R.j[rn].addb = addb; R.j[rn].bias = bias;
        R.j[rn].gather = gather;
        R.t0[rn] = rtt; rtt += (MO8 + 255) / 256; ++rn;
    };
    auto rLaunch = [&](const int* eidx, const float* gP, int gKS) {
        R.nj = rn; R.t0[rn] = rtt; R.eidx = eidx; R.gP = gP; R.gKS = gKS;
        hipLaunchKernelGGL(k_reduce, dim3(rtt), dim3(256), 0, stream, R);
        rn = 0; rtt = 0;
    };

    // ---- setup ----
    {
        ConvBatch cb;
        const float* srcs[7] = {W_ctx, W_relu, W_relc, W_node, W_factor, relvis, visual};
        unsigned short* dsts[7] = {Wb_ctx, Wb_relu, Wb_relc, Wb_node, Wb_factor, relvis_b, visual_b};
        const int nel[7] = {3 * 1024 * 1024, 3 * 1024 * 1024, 2 * 1024 * 1024,
                            2 * 1024 * 1024, 2 * 1024 * 1024, 1024 * 1024, 64 * 1024};
        int cum = 0;
        for (int k = 0; k < 7; ++k) { cb.s[k] = srcs[k]; cb.d[k] = dsts[k]; cb.beg8[k] = cum; cum += nel[k] / 8; }
        cb.total8 = cum;
        hipLaunchKernelGGL(k_f2b_batch, dim3((cum + 255) / 256), dim3(256), 0, stream, cb);
    }
    {
        T4 t4;
        t4.s[0] = W_sub; t4.d[0] = WsubT;
        t4.s[1] = W_obj; t4.d[1] = WobjT;
        t4.s[2] = W_r2s; t4.d[2] = Wr2sT;
        t4.s[3] = W_r2o; t4.d[3] = Wr2oT;
        hipLaunchKernelGGL(k_transpose, dim3(16, 16, 4), dim3(256), 0, stream, t4);
    }
    hipLaunchKernelGGL(k_buildW, dim3(1024, 1, 2), dim3(256), 0, stream,
                       W_relj, W_joint, WrtRel, WeffRel, UrtVj, UeffVj);

    const size_t PB1 = (size_t)4 * 1024 * 1024;   // bf16 elems per KS=4 M=1024 job
    // S4: Wc_s, Wc_o, R0, G0
    gAdd(seg1(Wr2sT), WsubT, 1024, partB, 1024, 1024, 4, 1);
    gAdd(seg1(Wr2oT), WobjT, 1024, partB + PB1, 1024, 1024, 4, 1);
    gAdd(seg1(relvis_b), WrtRel, 1024, partB + 2 * PB1, 1024, 1024, 4, 1);
    gAdd(seg1(visual_b), UrtVj, 1024, partF, 64, 1024, 4, 0);
    gLaunch();
    // S5
    rAdd(partB, 131072, 4, 1, nullptr, Wc_s, nullptr, nullptr, 0);
    rAdd(partB + PB1, 131072, 4, 1, nullptr, Wc_o, nullptr, nullptr, 0);
    rAdd(partB + 2 * PB1, 131072, 4, 1, nullptr, R0_b, nullptr, nullptr, 0);
    rAdd(partF, 8192, 4, 0, nullptr, G0_b, nullptr, nullptr, 0);
    rLaunch(nullptr, nullptr, 0);

    // ---- T iterations ----
    for (int t = 0; t < kT; ++t) {
        const unsigned short* vcur  = (t == 0) ? visual_b : vctx_bA;
        unsigned short*       vnext = (t == 0) ? vctx_bA : vctx_bB;
        const unsigned short* rccur = (t == 0) ? relvis_b : rc_bA;
        unsigned short*       rcnext = (t == 0) ? rc_bA : rc_bB;

        // L1: vj (f32 partials, skinny) + rj (bf16 partials, big)
        gAdd(prodA(vcur, visual_b), UeffVj, 2048, partF, 64, 2048, 8, 0);
        gAdd(prodA(rccur, relvis_b), WeffRel, 2048, partB, 1024, 2048, 8, 1);
        gLaunch();
        // L2: vj = G0 + sum -> bf16 ; rj = R0 + sum -> bf16
        rAdd(partF, 8192, 8, 0, nullptr, vj_b, G0_b, nullptr, 0);
        rAdd(partB, 131072, 8, 1, nullptr, rj_b, R0_b, nullptr, 0);
        rLaunch(nullptr, nullptr, 0);

        // L3: asqw (4 skinny, f32 KS=2) + relj (bf16 KS=4, big)
        gAdd(seg1(vj_b), Wb_relu,        3072, partF,          64, 1024, 2, 0);  // a_s
        gAdd(seg1(vj_b), Wb_relu + 1024, 3072, partF + 131072, 64, 1024, 2, 0);  // a_o
        gAdd(seg1(vj_b), Wc_s,           1024, partF + 262144, 64, 1024, 2, 0);  // qW_s
        gAdd(seg1(vj_b), Wc_o,           1024, partF + 393216, 64, 1024, 2, 0);  // qW_o
        gAdd(seg1(rj_b), Wb_relu + 2048, 3072, partB,        1024, 1024, 4, 1);  // relj
        gLaunch();
        // L4: asqw sums + relj (sum + gather a_s/a_o from f32 partials)
        rAdd(partF,          8192, 2, 0, asqw,          nullptr, nullptr, nullptr, 0);
        rAdd(partF + 131072, 8192, 2, 0, asqw + 65536,  nullptr, nullptr, nullptr, 0);
        rAdd(partF + 262144, 8192, 2, 0, asqw + 131072, nullptr, nullptr, nullptr, 0);
        rAdd(partF + 393216, 8192, 2, 0, asqw + 196608, nullptr, nullptr, nullptr, 0);
        rAdd(partB, 131072, 4, 1, relj, relj_b, nullptr, nullptr, 1);
        rLaunch(edge_idx, partF, 2);

        // merged scores + softmax + aggregation (bf16 ctx out)
        hipLaunchKernelGGL(k_sctx, dim3(128), dim3(256), 0, stream,
                           relj, asqw + 131072, asqw + 196608, conn, ctx1_b, ctx2_b);

        // L7: vctx' + rc'
        gAdd(seg3(vcur, ctx1_b, ctx2_b), Wb_ctx, 3072, partF, 64, 3072, 8, 0);
        gAdd(seg2(rccur, relj_b), Wb_relc, 2048, partB, 1024, 2048, 8, 1);
        gLaunch();
        // L8
        rAdd(partF, 8192, 8, 0, nullptr, vnext, nullptr, nullptr, 0);
        rAdd(partB, 131072, 8, 1, nullptr, rcnext, nullptr, nullptr, 0);
        rLaunch(nullptr, nullptr, 0);
    }

    float* rel_out = (float*)d_out;
    float* v_out   = (float*)d_out + (size_t)kE * kD;
    // F1: rel_out (bf16 partials KS=4, big) + v_out (f32 partials KS=8, skinny)
    gAdd(seg2(relvis_b, rc_bB), Wb_factor, 2048, partB, 1024, 2048, 4, 1);
    gAdd(seg2(visual_b, vctx_bB), Wb_node, 2048, partF, 64, 2048, 8, 0);
    gLaunch();
    // F2
    rAdd(partB, 131072, 4, 1, rel_out, nullptr, nullptr, nullptr, 0);
    rAdd(partF, 8192, 8, 0, v_out, nullptr, nullptr, b_node, 0);
    rLaunch(nullptr, nullptr, 0);
}

// Round 9
// 230.038 us; speedup vs baseline: 1.2110x; 1.2110x over previous
//
#include <hip/hip_runtime.h>

// ---- problem constants ----
static constexpr int kN = 64;    // nodes
static constexpr int kD = 1024;  // feature dim
static constexpr int kE = 1024;  // edges (16 per row, row-major by (i,j))
static constexpr int kT = 2;     // iterations

typedef short  bf16x8 __attribute__((ext_vector_type(8)));
typedef float  f32x4  __attribute__((ext_vector_type(4)));
typedef unsigned short us8 __attribute__((ext_vector_type(8)));
typedef unsigned short us4 __attribute__((ext_vector_type(4)));

__device__ __forceinline__ unsigned short f2b(float f) {
    unsigned int u = __builtin_bit_cast(unsigned int, f);
    u += 0x7FFFu + ((u >> 16) & 1u);          // RNE
    return (unsigned short)(u >> 16);
}
__device__ __forceinline__ float b2f(unsigned short u) {
    unsigned int x = ((unsigned int)u) << 16;
    return __builtin_bit_cast(float, x);
}
__device__ __forceinline__ bf16x8 cvt8(float4 a, float4 b) {
    us8 o;
    o[0] = f2b(a.x); o[1] = f2b(a.y); o[2] = f2b(a.z); o[3] = f2b(a.w);
    o[4] = f2b(b.x); o[5] = f2b(b.y); o[6] = f2b(b.z); o[7] = f2b(b.w);
    return __builtin_bit_cast(bf16x8, o);
}

// A-operand source, ALL bf16 [row][1024] segments:
// mode 1: concat of segments s0|s1|s2 ; mode 2: [s0 | s0*s1]
struct ASrc { const unsigned short* s0; const unsigned short* s1; const unsigned short* s2; int mode; };

__device__ __forceinline__ bf16x8 loadA8(const ASrc& s, int row, int kg) {
    const int seg = kg >> 10, k = kg & 1023;
    const size_t ro = (size_t)row * 1024 + k;
    if (s.mode == 1) {
        const unsigned short* p = (seg == 0) ? s.s0 : (seg == 1 ? s.s1 : s.s2);
        return *(const bf16x8*)(p + ro);
    }
    const bf16x8 a = *(const bf16x8*)(s.s0 + ro);
    if (seg == 0) return a;
    const bf16x8 b = *(const bf16x8*)(s.s1 + ro);
    const us8 ua = __builtin_bit_cast(us8, a), ub = __builtin_bit_cast(us8, b);
    us8 o;
#pragma unroll
    for (int q = 0; q < 8; ++q) o[q] = f2b(b2f(ua[q]) * b2f(ub[q]));
    return __builtin_bit_cast(bf16x8, o);
}

// =====================================================================
// Job-list MFMA GEMM.
// BIG path (M>=128): 128x128 tile, 4 waves (2x2) each 64x64, BOTH operands
//   staged through swizzled LDS (coalesced). 0.5 ds_read per MFMA.
//   bf16 partials via LDS-coalesced epilogue.
// SKINNY path (M=64): 64x128 tile (A+B via LDS), f32 partials.
// Block decode: row-tile fastest -> XCD-affine A reuse in L2.
// =====================================================================
struct GJob { ASrc a; const unsigned short* W; int ldw; void* P; int M; int K; int KS; int pbf; };
struct GJobs { GJob j[5]; int t0[6]; int nj; };

__global__ __launch_bounds__(256)
void k_gemm(GJobs G)
{
    __shared__ unsigned short lds[16896];   // big: As[128][64] | Bs[128][64]; epi Cs[128][132]
    const int flat = blockIdx.x;
    int ji = 0;
    while (ji + 1 < G.nj && flat >= G.t0[ji + 1]) ++ji;
    const GJob J = G.j[ji];
    const int local = flat - G.t0[ji];
    const int tid = threadIdx.x, lane = tid & 63, wid = tid >> 6;
    const int l15 = lane & 15, l4 = lane >> 4;
    const int sr = tid >> 3, sc8 = tid & 7;
    const int wc8 = (sc8 ^ (sr & 7)) * 8;

    if (J.M >= 128) {
        // ---------------- BIG: 128x128, both via LDS ----------------
        const int rowTiles = J.M >> 7;
        const int rt = local % rowTiles;
        const int rest = local / rowTiles;
        const int ct = rest & 7, z = rest >> 3;
        const int rowBase = rt * 128, colBase = ct * 128;
        const int kchunk = J.K / J.KS, kbeg = z * kchunk, kend = kbeg + kchunk;
        const int wr = wid >> 1, wc = wid & 1;

        f32x4 acc[4][4] = {};
        bf16x8 ra[4], rb[4];
        auto stage = [&](int kt) {
#pragma unroll
            for (int h = 0; h < 4; ++h) {
                ra[h] = loadA8(J.a, rowBase + sr + 32 * h, kt + sc8 * 8);
                rb[h] = *(const bf16x8*)(J.W + (size_t)(colBase + sr + 32 * h) * J.ldw + kt + sc8 * 8);
            }
        };

        stage(kbeg);
        for (int kt = kbeg; kt < kend; kt += 64) {
            __syncthreads();
#pragma unroll
            for (int h = 0; h < 4; ++h) {
                *(bf16x8*)&lds[(sr + 32 * h) * 64 + wc8] = ra[h];
                *(bf16x8*)&lds[8192 + (sr + 32 * h) * 64 + wc8] = rb[h];
            }
            __syncthreads();
            if (kt + 64 < kend) stage(kt + 64);
#pragma unroll
            for (int kk = 0; kk < 2; ++kk) {
                bf16x8 af[4], bv[4];
#pragma unroll
                for (int m = 0; m < 4; ++m) {
                    const int ar = wr * 64 + m * 16 + l15;
                    af[m] = *(const bf16x8*)&lds[ar * 64 + (((kk << 2) | l4) ^ (ar & 7)) * 8];
                }
#pragma unroll
                for (int n = 0; n < 4; ++n) {
                    const int br = wc * 64 + n * 16 + l15;
                    bv[n] = *(const bf16x8*)&lds[8192 + br * 64 + (((kk << 2) | l4) ^ (br & 7)) * 8];
                }
#pragma unroll
                for (int m = 0; m < 4; ++m)
#pragma unroll
                    for (int n = 0; n < 4; ++n)
                        acc[m][n] = __builtin_amdgcn_mfma_f32_16x16x32_bf16(af[m], bv[n], acc[m][n], 0, 0, 0);
            }
        }

        // bf16 partial epilogue via LDS (coalesced)
        __syncthreads();
#pragma unroll
        for (int m = 0; m < 4; ++m)
#pragma unroll
            for (int n = 0; n < 4; ++n)
#pragma unroll
                for (int r = 0; r < 4; ++r)
                    lds[(wr * 64 + m * 16 + l4 * 4 + r) * 132 + wc * 64 + n * 16 + l15] =
                        f2b(acc[m][n][r]);
        __syncthreads();
        unsigned short* Pb = (unsigned short*)J.P + (size_t)z * J.M * 1024;
#pragma unroll
        for (int c = tid; c < 2048; c += 256) {
            const int row = c >> 4, ch = c & 15;
            *(bf16x8*)(Pb + (size_t)(rowBase + row) * 1024 + colBase + ch * 8) =
                *(const bf16x8*)&lds[row * 132 + ch * 8];
        }
    } else {
        // ---------------- SKINNY: 64x128, f32 partials ----------------
        const int ct = local & 7, z = local >> 3;
        const int colBase = ct * 128;
        const int kchunk = J.K / J.KS, kbeg = z * kchunk, kend = kbeg + kchunk;
        const int wr = wid >> 1, wc = wid & 1;

        bf16x8 ra[2], rb[4];
        auto stage = [&](int kt) {
#pragma unroll
            for (int h = 0; h < 2; ++h)
                ra[h] = loadA8(J.a, sr + 32 * h, kt + sc8 * 8);
#pragma unroll
            for (int h = 0; h < 4; ++h)
                rb[h] = *(const bf16x8*)(J.W + (size_t)(colBase + sr + 32 * h) * J.ldw + kt + sc8 * 8);
        };

        f32x4 acc[2][4] = {};
        stage(kbeg);
        for (int kt = kbeg; kt < kend; kt += 64) {
            __syncthreads();
#pragma unroll
            for (int h = 0; h < 2; ++h)
                *(bf16x8*)&lds[(sr + 32 * h) * 64 + wc8] = ra[h];
#pragma unroll
            for (int h = 0; h < 4; ++h)
                *(bf16x8*)&lds[4096 + (sr + 32 * h) * 64 + wc8] = rb[h];
            __syncthreads();
            if (kt + 64 < kend) stage(kt + 64);
#pragma unroll
            for (int kk = 0; kk < 2; ++kk) {
                const int c8 = kk * 4 + l4;
                bf16x8 af[2], bv[4];
#pragma unroll
                for (int m = 0; m < 2; ++m) {
                    const int ar = wr * 32 + m * 16 + l15;
                    af[m] = *(const bf16x8*)&lds[ar * 64 + (c8 ^ (ar & 7)) * 8];
                }
#pragma unroll
                for (int n = 0; n < 4; ++n) {
                    const int br = wc * 64 + n * 16 + l15;
                    bv[n] = *(const bf16x8*)&lds[4096 + br * 64 + (c8 ^ (br & 7)) * 8];
                }
#pragma unroll
                for (int m = 0; m < 2; ++m)
#pragma unroll
                    for (int n = 0; n < 4; ++n)
                        acc[m][n] = __builtin_amdgcn_mfma_f32_16x16x32_bf16(af[m], bv[n], acc[m][n], 0, 0, 0);
            }
        }
        float* base = (float*)J.P + (size_t)z * J.M * 1024;
#pragma unroll
        for (int m = 0; m < 2; ++m) {
            const int row = wr * 32 + m * 16 + l4 * 4;
#pragma unroll
            for (int n = 0; n < 4; ++n) {
                const int col = colBase + wc * 64 + n * 16 + l15;
#pragma unroll
                for (int r = 0; r < 4; ++r)
                    base[(size_t)(row + r) * 1024 + col] = acc[m][n][r];
            }
        }
    }
}

// =====================================================================
// Job-list split-K reduce, 8-elem granularity.
// out = sum_z P[z] (+addb bf16) (+bias) (+gather a_s/a_o from f32 partials)
// =====================================================================
struct RJob { const void* P; int MO8; int KS; int pbf; float* Cf; unsigned short* Cb;
              const unsigned short* addb; const float* bias; int gather; };
struct RJobs { RJob j[6]; int t0[7]; int nj; const int* eidx; const float* gP; int gKS; };

__global__ void k_reduce(RJobs R)
{
    const int flat = blockIdx.x;
    int ji = 0;
    while (ji + 1 < R.nj && flat >= R.t0[ji + 1]) ++ji;
    const RJob J = R.j[ji];
    const int i8 = (flat - R.t0[ji]) * 256 + threadIdx.x;
    if (i8 >= J.MO8) return;
    float s[8] = {0.f, 0.f, 0.f, 0.f, 0.f, 0.f, 0.f, 0.f};
    if (J.pbf) {
        const unsigned short* P = (const unsigned short*)J.P;
        for (int z = 0; z < J.KS; ++z) {
            const us8 v = *(const us8*)(P + (size_t)z * J.MO8 * 8 + (size_t)i8 * 8);
#pragma unroll
            for (int q = 0; q < 8; ++q) s[q] += b2f(v[q]);
        }
    } else {
        const float* P = (const float*)J.P;
        for (int z = 0; z < J.KS; ++z) {
            const float* p = P + (size_t)z * J.MO8 * 8 + (size_t)i8 * 8;
            const float4 v0 = *(const float4*)p;
            const float4 v1 = *(const float4*)(p + 4);
            s[0] += v0.x; s[1] += v0.y; s[2] += v0.z; s[3] += v0.w;
            s[4] += v1.x; s[5] += v1.y; s[6] += v1.z; s[7] += v1.w;
        }
    }
    if (J.addb) {
        const us8 v = *(const us8*)(J.addb + (size_t)i8 * 8);
#pragma unroll
        for (int q = 0; q < 8; ++q) s[q] += b2f(v[q]);
    }
    if (J.gather) {
        const int e = i8 >> 7, c8 = i8 & 127;
        const int idx = R.eidx[e];
        const float* as_ = R.gP + (size_t)(idx >> 6) * 1024 + c8 * 8;
        const float* ao_ = R.gP + 131072 + (size_t)(idx & 63) * 1024 + c8 * 8;
        for (int z = 0; z < R.gKS; ++z) {
#pragma unroll
            for (int q = 0; q < 8; ++q)
                s[q] += as_[(size_t)z * 65536 + q] + ao_[(size_t)z * 65536 + q];
        }
    }
    if (J.bias) {
        const int c8 = i8 & 127;
#pragma unroll
        for (int q = 0; q < 8; ++q) s[q] += J.bias[c8 * 8 + q];
    }
    if (J.Cf) {
        *(float4*)(J.Cf + (size_t)i8 * 8)     = make_float4(s[0], s[1], s[2], s[3]);
        *(float4*)(J.Cf + (size_t)i8 * 8 + 4) = make_float4(s[4], s[5], s[6], s[7]);
    }
    if (J.Cb) {
        us8 o;
#pragma unroll
        for (int q = 0; q < 8; ++q) o[q] = f2b(s[q]);
        *(us8*)(J.Cb + (size_t)i8 * 8) = o;
    }
}

// batched f32 -> bf16 conversion (7 matrices), one launch
struct ConvBatch { const float* s[7]; unsigned short* d[7]; int beg8[7]; int total8; };
__global__ void k_f2b_batch(ConvBatch cb)
{
    int i = blockIdx.x * blockDim.x + threadIdx.x;
    if (i >= cb.total8) return;
    int k = 0;
    while (k < 6 && i >= cb.beg8[k + 1]) ++k;
    const int j = i - cb.beg8[k];
    const float4 v0 = reinterpret_cast<const float4*>(cb.s[k])[2 * j];
    const float4 v1 = reinterpret_cast<const float4*>(cb.s[k])[2 * j + 1];
    const bf16x8 o = cvt8(v0, v1);
    *(bf16x8*)(cb.d[k] + (size_t)j * 8) = o;
}

// transpose 4 f32 [1024][1024] matrices into bf16 (dst[k][o] = src[o][k])
struct T4 { const float* s[4]; unsigned short* d[4]; };
__global__ __launch_bounds__(256)
void k_transpose(T4 t4)
{
    __shared__ float tile[64][65];
    const float* __restrict__ src = t4.s[blockIdx.z];
    unsigned short* __restrict__ dst = t4.d[blockIdx.z];
    const int bx = blockIdx.x * 64, by = blockIdx.y * 64;
    const int c = threadIdx.x & 63, r0 = threadIdx.x >> 6;
#pragma unroll
    for (int h = 0; h < 16; ++h) {
        const int r = r0 * 16 + h;
        tile[r][c] = src[(size_t)(by + r) * 1024 + bx + c];
    }
    __syncthreads();
#pragma unroll
    for (int h = 0; h < 16; ++h) {
        const int kk = r0 * 16 + h;
        dst[(size_t)(bx + kk) * 1024 + by + c] = f2b(tile[c][kk]);
    }
}

// build folded joint weights from W (1024 x 4096, slices W1|W2|W3|W4):
// z=0 (rel, s=+1):  rt = W1+W4,  eff = [W2-W4 | W3]
// z=1 (vj,  s=-1):  rt = W1-W4,  eff = [W2+W4 | W3]
__global__ __launch_bounds__(256)
void k_buildW(const float* __restrict__ Wrel, const float* __restrict__ Wjnt,
              unsigned short* __restrict__ WrtRel, unsigned short* __restrict__ WeffRel,
              unsigned short* __restrict__ UrtVj, unsigned short* __restrict__ UeffVj)
{
    const int idx = blockIdx.x * 256 + threadIdx.x;     // [0, 1024*256)
    const int o = idx >> 8, j = (idx & 255) * 4;
    const float* W = blockIdx.z ? Wjnt : Wrel;
    const float sgn = blockIdx.z ? -1.f : 1.f;
    unsigned short* rt = blockIdx.z ? UrtVj : WrtRel;
    unsigned short* ef = blockIdx.z ? UeffVj : WeffRel;
    const float4 w1 = *(const float4*)(W + (size_t)o * 4096 + j);
    const float4 w2 = *(const float4*)(W + (size_t)o * 4096 + 1024 + j);
    const float4 w3 = *(const float4*)(W + (size_t)o * 4096 + 2048 + j);
    const float4 w4 = *(const float4*)(W + (size_t)o * 4096 + 3072 + j);
    us4 t;
    t.x = f2b(w1.x + sgn * w4.x); t.y = f2b(w1.y + sgn * w4.y);
    t.z = f2b(w1.z + sgn * w4.z); t.w = f2b(w1.w + sgn * w4.w);
    *(us4*)(rt + (size_t)o * 1024 + j) = t;
    t.x = f2b(w2.x - sgn * w4.x); t.y = f2b(w2.y - sgn * w4.y);
    t.z = f2b(w2.z - sgn * w4.z); t.w = f2b(w2.w - sgn * w4.w);
    *(us4*)(ef + (size_t)o * 2048 + j) = t;
    t.x = f2b(w3.x); t.y = f2b(w3.y); t.z = f2b(w3.z); t.w = f2b(w3.w);
    *(us4*)(ef + (size_t)o * 2048 + 1024 + j) = t;
}

// =====================================================================
// merged scores + softmax + weighted aggregation.
// block i<64  : s[q] = <qws[i], relj[16i+q]>/32 ; ctx1[i] = softmax-weighted sum
// block j>=64 : s[i] = <qwo[j], relj[conn[i][j]]>/32 ; ctx2[j] likewise (col)
// =====================================================================
__global__ __launch_bounds__(256)
void k_sctx(const float* __restrict__ relj, const float* __restrict__ qws,
            const float* __restrict__ qwo, const int* __restrict__ conn,
            unsigned short* __restrict__ ctx1b, unsigned short* __restrict__ ctx2b)
{
    const int bid = blockIdx.x, t = threadIdx.x;
    const float4* relj4 = reinterpret_cast<const float4*>(relj);
    __shared__ float sl[64];
    __shared__ int el[64];
    float4 acc = make_float4(0.f, 0.f, 0.f, 0.f);

    if (bid < 64) {
        const int i = bid;
        {
            const int g = t >> 4, l = t & 15;          // edge i*16+g
            const size_t e4 = (size_t)(i * 16 + g) * 256;
            const float4* q4 = reinterpret_cast<const float4*>(qws) + (size_t)i * 256;
            float v = 0.f;
#pragma unroll
            for (int q = 0; q < 16; ++q) {
                const float4 r = relj4[e4 + l + q * 16];
                const float4 a = q4[l + q * 16];
                v += a.x * r.x + a.y * r.y + a.z * r.z + a.w * r.w;
            }
            v += __shfl_xor(v, 1, 16);
            v += __shfl_xor(v, 2, 16);
            v += __shfl_xor(v, 4, 16);
            v += __shfl_xor(v, 8, 16);
            if (l == 0) sl[g] = v * 0.03125f;
        }
        __syncthreads();
        float sv[16];
        float m = -1e30f;
#pragma unroll
        for (int q = 0; q < 16; ++q) { sv[q] = sl[q]; m = fmaxf(m, sv[q]); }
        float sum = 0.f;
#pragma unroll
        for (int q = 0; q < 16; ++q) { sv[q] = expf(sv[q] - m); sum += sv[q]; }
        const float inv = 1.f / sum;
#pragma unroll
        for (int q = 0; q < 16; ++q) {
            const float w = sv[q] * inv;
            const float4 v = relj4[(size_t)(i * 16 + q) * 256 + t];
            acc.x += w * v.x; acc.y += w * v.y; acc.z += w * v.z; acc.w += w * v.w;
        }
        us4 o; o.x = f2b(acc.x); o.y = f2b(acc.y); o.z = f2b(acc.z); o.w = f2b(acc.w);
        *(us4*)(ctx1b + (size_t)i * 1024 + t * 4) = o;
    } else {
        const int j = bid - 64;
        {
            const int i = t >> 2, sub = t & 3;
            const int e = conn[i * kN + j];
            if (sub == 0) el[i] = e;
            float v = 0.f;
            if (e >= 0) {
                const size_t e4 = (size_t)e * 256;
                const float4* q4 = reinterpret_cast<const float4*>(qwo) + (size_t)j * 256;
#pragma unroll
                for (int q = 0; q < 64; ++q) {
                    const float4 r = relj4[e4 + sub + q * 4];
                    const float4 a = q4[sub + q * 4];
                    v += a.x * r.x + a.y * r.y + a.z * r.z + a.w * r.w;
                }
            }
            v += __shfl_xor(v, 1, 4);
            v += __shfl_xor(v, 2, 4);
            if (sub == 0) sl[i] = (e >= 0) ? v * 0.03125f : -1e30f;
        }
        __syncthreads();
        float m = -1e30f;
        for (int i = 0; i < 64; ++i) m = fmaxf(m, sl[i]);
        float sum = 0.f;
        float ex[64];
        for (int i = 0; i < 64; ++i) {
            ex[i] = (el[i] >= 0) ? expf(sl[i] - m) : 0.f;
            sum += ex[i];
        }
        const float inv = 1.f / sum;
        for (int i = 0; i < 64; ++i) {
            const int e = el[i];
            if (e >= 0) {
                const float w = ex[i] * inv;
                const float4 v = relj4[(size_t)e * 256 + t];
                acc.x += w * v.x; acc.y += w * v.y; acc.z += w * v.z; acc.w += w * v.w;
            }
        }
        us4 o; o.x = f2b(acc.x); o.y = f2b(acc.y); o.z = f2b(acc.z); o.w = f2b(acc.w);
        *(us4*)(ctx2b + (size_t)j * 1024 + t * 4) = o;
    }
}

// =====================================================================
extern "C" void kernel_launch(void* const* d_in, const int* in_sizes, int n_in,
                              void* d_out, int out_size, void* d_ws, size_t ws_size,
                              hipStream_t stream)
{
    const float* visual   = (const float*)d_in[0];
    const float* relvis   = (const float*)d_in[1];
    const int*   conn     = (const int*)d_in[2];
    const int*   edge_idx = (const int*)d_in[4];
    const float* W_sub    = (const float*)d_in[5];
    const float* W_obj    = (const float*)d_in[6];
    const float* W_r2s    = (const float*)d_in[7];
    const float* W_r2o    = (const float*)d_in[8];
    const float* W_joint  = (const float*)d_in[9];
    const float* W_ctx    = (const float*)d_in[10];
    const float* W_relu   = (const float*)d_in[11];  // (D,3D): Ws|Wo|Wr
    const float* W_relj   = (const float*)d_in[12];
    const float* W_relc   = (const float*)d_in[13];
    const float* W_node   = (const float*)d_in[14];
    const float* b_node   = (const float*)d_in[15];
    const float* W_factor = (const float*)d_in[16];
    (void)in_sizes; (void)n_in; (void)out_size; (void)ws_size;

    float* ws = (float*)d_ws;
    size_t off = 0;
    auto allocF = [&](size_t n) { float* p = ws + off; off += n; return p; };
    auto allocU = [&](size_t n) { return (unsigned short*)allocF((n + 1) / 2); };

    float* partF = allocF((size_t)1024 * 1024);          // f32 partials (skinny)
    unsigned short* partB = allocU((size_t)16 * 1024 * 1024);  // bf16 partials
    float* asqw  = allocF((size_t)4 * 64 * 1024);        // a_s | a_o | qW_s | qW_o (f32)
    float* relj  = allocF((size_t)kE * kD);
    unsigned short* relvis_b = allocU((size_t)kE * kD);
    unsigned short* visual_b = allocU((size_t)kN * kD);
    unsigned short* vj_b   = allocU((size_t)kN * kD);
    unsigned short* rj_b   = allocU((size_t)kE * kD);
    unsigned short* relj_b = allocU((size_t)kE * kD);
    unsigned short* rc_bA  = allocU((size_t)kE * kD);
    unsigned short* rc_bB  = allocU((size_t)kE * kD);
    unsigned short* vctx_bA = allocU((size_t)kN * kD);
    unsigned short* vctx_bB = allocU((size_t)kN * kD);
    unsigned short* ctx1_b = allocU((size_t)kN * kD);
    unsigned short* ctx2_b = allocU((size_t)kN * kD);
    unsigned short* R0_b = allocU((size_t)kE * kD);
    unsigned short* G0_b = allocU((size_t)kN * kD);
    unsigned short* Wb_ctx    = allocU((size_t)kD * 3 * kD);
    unsigned short* Wb_relu   = allocU((size_t)kD * 3 * kD);
    unsigned short* Wb_relc   = allocU((size_t)kD * 2 * kD);
    unsigned short* Wb_node   = allocU((size_t)kD * 2 * kD);
    unsigned short* Wb_factor = allocU((size_t)kD * 2 * kD);
    unsigned short* WsubT = allocU((size_t)kD * kD);
    unsigned short* WobjT = allocU((size_t)kD * kD);
    unsigned short* Wr2sT = allocU((size_t)kD * kD);
    unsigned short* Wr2oT = allocU((size_t)kD * kD);
    unsigned short* Wc_s  = allocU((size_t)kD * kD);
    unsigned short* Wc_o  = allocU((size_t)kD * kD);
    unsigned short* WrtRel  = allocU((size_t)kD * kD);      // W1+W4
    unsigned short* WeffRel = allocU((size_t)kD * 2 * kD);  // [W2-W4 | W3]
    unsigned short* UrtVj   = allocU((size_t)kD * kD);      // U1-U4
    unsigned short* UeffVj  = allocU((size_t)kD * 2 * kD);  // [U2+U4 | U3]

    auto seg1 = [](const unsigned short* a) {
        ASrc s; s.s0 = a; s.s1 = nullptr; s.s2 = nullptr; s.mode = 1; return s;
    };
    auto seg2 = [](const unsigned short* a, const unsigned short* b) {
        ASrc s; s.s0 = a; s.s1 = b; s.s2 = nullptr; s.mode = 1; return s;
    };
    auto seg3 = [](const unsigned short* a, const unsigned short* b, const unsigned short* c) {
        ASrc s; s.s0 = a; s.s1 = b; s.s2 = c; s.mode = 1; return s;
    };
    auto prodA = [](const unsigned short* c, const unsigned short* x) {  // [c | c*x]
        ASrc s; s.s0 = c; s.s1 = x; s.s2 = nullptr; s.mode = 2; return s;
    };

    // ---- job-list launch helpers ----
    GJobs G; RJobs R;
    int gn = 0, gt = 0, rn = 0, rtt = 0;
    auto gAdd = [&](ASrc a, const unsigned short* W, int ldw, void* P, int M, int K, int KS, int pbf) {
        G.j[gn].a = a; G.j[gn].W = W; G.j[gn].ldw = ldw; G.j[gn].P = P;
        G.j[gn].M = M; G.j[gn].K = K; G.j[gn].KS = KS; G.j[gn].pbf = pbf;
        G.t0[gn] = gt;
        gt += (M >= 128) ? KS * (M >> 7) * 8 : KS * 8;
        ++gn;
    };
    auto gLaunch = [&]() {
        G.nj = gn; G.t0[gn] = gt;
        hipLaunchKernelGGL(k_gemm, dim3(gt), dim3(256), 0, stream, G);
        gn = 0; gt = 0;
    };
    auto rAdd = [&](const void* P, int MO8, int KS, int pbf, float* Cf, unsigned short* Cb,
                    const unsigned short* addb, const float* bias, int gather) {
        R.j[rn].P = P; R.j[rn].MO8 = MO8; R.j[rn].KS = KS; R.j[rn].pbf = pbf;
        R.j[rn].Cf = Cf; R.j[rn].Cb = Cb; R.j[rn].addb = addb; R.j[rn].bias = bias;
        R.j[rn].gather = gather;
        R.t0[rn] = rtt; rtt += (MO8 + 255) / 256; ++rn;
    };
    auto rLaunch = [&](const int* eidx, const float* gP, int gKS) {
        R.nj = rn; R.t0[rn] = rtt; R.eidx = eidx; R.gP = gP; R.gKS = gKS;
        hipLaunchKernelGGL(k_reduce, dim3(rtt), dim3(256), 0, stream, R);
        rn = 0; rtt = 0;
    };

    // ---- setup ----
    {
        ConvBatch cb;
        const float* srcs[7] = {W_ctx, W_relu, W_relc, W_node, W_factor, relvis, visual};
        unsigned short* dsts[7] = {Wb_ctx, Wb_relu, Wb_relc, Wb_node, Wb_factor, relvis_b, visual_b};
        const int nel[7] = {3 * 1024 * 1024, 3 * 1024 * 1024, 2 * 1024 * 1024,
                            2 * 1024 * 1024, 2 * 1024 * 1024, 1024 * 1024, 64 * 1024};
        int cum = 0;
        for (int k = 0; k < 7; ++k) { cb.s[k] = srcs[k]; cb.d[k] = dsts[k]; cb.beg8[k] = cum; cum += nel[k] / 8; }
        cb.total8 = cum;
        hipLaunchKernelGGL(k_f2b_batch, dim3((cum + 255) / 256), dim3(256), 0, stream, cb);
    }
    {
        T4 t4;
        t4.s[0] = W_sub; t4.d[0] = WsubT;
        t4.s[1] = W_obj; t4.d[1] = WobjT;
        t4.s[2] = W_r2s; t4.d[2] = Wr2sT;
        t4.s[3] = W_r2o; t4.d[3] = Wr2oT;
        hipLaunchKernelGGL(k_transpose, dim3(16, 16, 4), dim3(256), 0, stream, t4);
    }
    hipLaunchKernelGGL(k_buildW, dim3(1024, 1, 2), dim3(256), 0, stream,
                       W_relj, W_joint, WrtRel, WeffRel, UrtVj, UeffVj);

    const size_t PB1 = (size_t)4 * 1024 * 1024;   // bf16 elems per KS=4 M=1024 job
    // S4: Wc_s, Wc_o, R0, G0
    gAdd(seg1(Wr2sT), WsubT, 1024, partB, 1024, 1024, 4, 1);
    gAdd(seg1(Wr2oT), WobjT, 1024, partB + PB1, 1024, 1024, 4, 1);
    gAdd(seg1(relvis_b), WrtRel, 1024, partB + 2 * PB1, 1024, 1024, 4, 1);
    gAdd(seg1(visual_b), UrtVj, 1024, partF, 64, 1024, 4, 0);
    gLaunch();
    // S5
    rAdd(partB, 131072, 4, 1, nullptr, Wc_s, nullptr, nullptr, 0);
    rAdd(partB + PB1, 131072, 4, 1, nullptr, Wc_o, nullptr, nullptr, 0);
    rAdd(partB + 2 * PB1, 131072, 4, 1, nullptr, R0_b, nullptr, nullptr, 0);
    rAdd(partF, 8192, 4, 0, nullptr, G0_b, nullptr, nullptr, 0);
    rLaunch(nullptr, nullptr, 0);

    // ---- T iterations ----
    for (int t = 0; t < kT; ++t) {
        const unsigned short* vcur  = (t == 0) ? visual_b : vctx_bA;
        unsigned short*       vnext = (t == 0) ? vctx_bA : vctx_bB;
        const unsigned short* rccur = (t == 0) ? relvis_b : rc_bA;
        unsigned short*       rcnext = (t == 0) ? rc_bA : rc_bB;

        // L1: vj (f32 partials, skinny) + rj (bf16 partials, big)
        gAdd(prodA(vcur, visual_b), UeffVj, 2048, partF, 64, 2048, 8, 0);
        gAdd(prodA(rccur, relvis_b), WeffRel, 2048, partB, 1024, 2048, 8, 1);
        gLaunch();
        // L2: vj = G0 + sum -> bf16 ; rj = R0 + sum -> bf16
        rAdd(partF, 8192, 8, 0, nullptr, vj_b, G0_b, nullptr, 0);
        rAdd(partB, 131072, 8, 1, nullptr, rj_b, R0_b, nullptr, 0);
        rLaunch(nullptr, nullptr, 0);

        // L3: asqw (4 skinny, f32 KS=2) + relj (bf16 KS=4, big)
        gAdd(seg1(vj_b), Wb_relu,        3072, partF,          64, 1024, 2, 0);  // a_s
        gAdd(seg1(vj_b), Wb_relu + 1024, 3072, partF + 131072, 64, 1024, 2, 0);  // a_o
        gAdd(seg1(vj_b), Wc_s,           1024, partF + 262144, 64, 1024, 2, 0);  // qW_s
        gAdd(seg1(vj_b), Wc_o,           1024, partF + 393216, 64, 1024, 2, 0);  // qW_o
        gAdd(seg1(rj_b), Wb_relu + 2048, 3072, partB,        1024, 1024, 4, 1);  // relj
        gLaunch();
        // L4: asqw sums + relj (sum + gather a_s/a_o from f32 partials)
        rAdd(partF,          8192, 2, 0, asqw,          nullptr, nullptr, nullptr, 0);
        rAdd(partF + 131072, 8192, 2, 0, asqw + 65536,  nullptr, nullptr, nullptr, 0);
        rAdd(partF + 262144, 8192, 2, 0, asqw + 131072, nullptr, nullptr, nullptr, 0);
        rAdd(partF + 393216, 8192, 2, 0, asqw + 196608, nullptr, nullptr, nullptr, 0);
        rAdd(partB, 131072, 4, 1, relj, relj_b, nullptr, nullptr, 1);
        rLaunch(edge_idx, partF, 2);

        // merged scores + softmax + aggregation (bf16 ctx out)
        hipLaunchKernelGGL(k_sctx, dim3(128), dim3(256), 0, stream,
                           relj, asqw + 131072, asqw + 196608, conn, ctx1_b, ctx2_b);

        // L7: vctx' + rc'
        gAdd(seg3(vcur, ctx1_b, ctx2_b), Wb_ctx, 3072, partF, 64, 3072, 8, 0);
        gAdd(seg2(rccur, relj_b), Wb_relc, 2048, partB, 1024, 2048, 8, 1);
        gLaunch();
        // L8
        rAdd(partF, 8192, 8, 0, nullptr, vnext, nullptr, nullptr, 0);
        rAdd(partB, 131072, 8, 1, nullptr, rcnext, nullptr, nullptr, 0);
        rLaunch(nullptr, nullptr, 0);
    }

    float* rel_out = (float*)d_out;
    float* v_out   = (float*)d_out + (size_t)kE * kD;
    // F1: rel_out (bf16 partials KS=4, big) + v_out (f32 partials KS=8, skinny)
    gAdd(seg2(relvis_b, rc_bB), Wb_factor, 2048, partB, 1024, 2048, 4, 1);
    gAdd(seg2(visual_b, vctx_bB), Wb_node, 2048, partF, 64, 2048, 8, 0);
    gLaunch();
    // F2
    rAdd(partB, 131072, 4, 1, rel_out, nullptr, nullptr, nullptr, 0);
    rAdd(partF, 8192, 8, 0, v_out, nullptr, nullptr, b_node, 0);
    rLaunch(nullptr, nullptr, 0);
}